// Round 4
// baseline (384.835 us; speedup 1.0000x reference)
//
#include <hip/hip_runtime.h>
#include <cstdint>
#include <cstddef>
#include <cfloat>

// Problem constants (match reference)
static constexpr int BATCH = 32;
static constexpr int KJ    = 17;   // heat channels (joints)
static constexpr int LL    = 19;   // limbs
static constexpr int HH    = 160;
static constexpr int WW    = 160;
static constexpr int PPK   = 30;   // top-k peaks
static constexpr int SS    = 10;   // samples along limb
static constexpr int HW    = HH * WW;
static constexpr int CGW   = WW / 4;        // 40 float4 cells per row
static constexpr int CAP   = 4096;          // candidate capacity per channel (LDS)

// conn quarter-plane staging
static constexpr int QROWS = 40;            // quarter-plane rows
static constexpr int QCNT  = QROWS * WW;    // 6400 floats = 25.6 KB
static constexpr int QF4   = QCNT / 4;      // 1600 float4

__constant__ int d_ska[LL] = {15,13,16,14,11,5,6,5,5,6,7,8,1,0,0,1,2,3,4};
__constant__ int d_skb[LL] = {13,11,14,12,12,11,12,6,7,8,9,10,2,1,2,3,4,5,6};
// t = linspace(0,1,10) in f32 (verified identical to f32(s/9.0))
__constant__ float d_ts[SS] = {
    0.0f,
    (float)(1.0/9.0), (float)(2.0/9.0), (float)(3.0/9.0),
    (float)(4.0/9.0), (float)(5.0/9.0), (float)(6.0/9.0),
    (float)(7.0/9.0), (float)(8.0/9.0),
    1.0f
};

__device__ __forceinline__ float max3f(float a, float b, float c) {
    return fmaxf(fmaxf(a, b), c);
}
__device__ __forceinline__ unsigned long long umax64(unsigned long long a, unsigned long long b) {
    return a > b ? a : b;
}

// ---------------------------------------------------------------------------
// Kernel 1: fused per-channel peak detection + top-30 + subpixel refine.
// One block of 512 threads (8 waves) per (b,k) channel. Branchless separable
// 3x3 max over float4 cells; ballot-aggregated append; per-wave register
// top-30; wave 0 merges 240->30. Writes (px,py,sc) to out[(ch*30+p)*3+..].
// ---------------------------------------------------------------------------
__global__ __launch_bounds__(512, 4) void peaks_kernel(const float* __restrict__ heat,
                                                       float* __restrict__ out)
{
    const int ch = blockIdx.x;              // b*17 + k
    const float* hp = heat + (size_t)ch * HW;

    __shared__ unsigned long long keys[CAP];
    __shared__ unsigned long long sel8[8 * PPK];
    __shared__ unsigned long long sel[PPK];
    __shared__ int cnt;

    const int tid  = threadIdx.x;
    const int lane = tid & 63;
    const int wave = tid >> 6;
    const unsigned long long ltmask = ((unsigned long long)1 << lane) - 1ull;

    if (tid == 0) cnt = 0;
    __syncthreads();

    // ---- branchless scan: 12.5 float4 cells per thread ----
    for (int c = tid; c < HW / 4; c += 512) {
        int y  = c / CGW;
        int cg = c - y * CGW;
        int x0 = cg * 4;
        int yu = (y > 0) ? y - 1 : 0;
        int yd = (y < HH - 1) ? y + 1 : HH - 1;

        const float* rc = hp + y  * WW + x0;
        const float* ru = hp + yu * WW + x0;
        const float* rd = hp + yd * WW + x0;

        float4 vc = *(const float4*)rc;
        float4 vu = *(const float4*)ru;
        float4 vd = *(const float4*)rd;
        bool hasL = (x0 > 0);
        bool hasR = (x0 + 4 < WW);
        float lc = hasL ? rc[-1] : -FLT_MAX;
        float lu = hasL ? ru[-1] : -FLT_MAX;
        float ld = hasL ? rd[-1] : -FLT_MAX;
        float rcx = hasR ? rc[4] : -FLT_MAX;
        float rux = hasR ? ru[4] : -FLT_MAX;
        float rdx = hasR ? rd[4] : -FLT_MAX;

        float mu0 = max3f(lu, vu.x, vu.y), mu1 = max3f(vu.x, vu.y, vu.z);
        float mu2 = max3f(vu.y, vu.z, vu.w), mu3 = max3f(vu.z, vu.w, rux);
        float mc0 = max3f(lc, vc.x, vc.y), mc1 = max3f(vc.x, vc.y, vc.z);
        float mc2 = max3f(vc.y, vc.z, vc.w), mc3 = max3f(vc.z, vc.w, rcx);
        float md0 = max3f(ld, vd.x, vd.y), md1 = max3f(vd.x, vd.y, vd.z);
        float md2 = max3f(vd.y, vd.z, vd.w), md3 = max3f(vd.z, vd.w, rdx);

        float nm0 = max3f(mu0, mc0, md0);
        float nm1 = max3f(mu1, mc1, md1);
        float nm2 = max3f(mu2, mc2, md2);
        float nm3 = max3f(mu3, mc3, md3);

        bool pk0 = (vc.x == nm0) && (vc.x > 0.1f);
        bool pk1 = (vc.y == nm1) && (vc.y > 0.1f);
        bool pk2 = (vc.z == nm2) && (vc.z > 0.1f);
        bool pk3 = (vc.w == nm3) && (vc.w > 0.1f);

        unsigned long long b0 = __ballot(pk0);
        unsigned long long b1 = __ballot(pk1);
        unsigned long long b2 = __ballot(pk2);
        unsigned long long b3 = __ballot(pk3);
        int c0 = __popcll(b0), c1 = __popcll(b1), c2 = __popcll(b2), c3 = __popcll(b3);
        int tot = c0 + c1 + c2 + c3;
        int base = 0;
        if (lane == 0 && tot > 0) base = atomicAdd(&cnt, tot);
        base = __shfl(base, 0);

        int idx0 = y * WW + x0;
        if (pk0) { int s = base + __popcll(b0 & ltmask); if (s < CAP)
            keys[s] = ((unsigned long long)__float_as_uint(vc.x) << 32) | (unsigned long long)(0xFFFFFFFFu - (unsigned)(idx0 + 0)); }
        if (pk1) { int s = base + c0 + __popcll(b1 & ltmask); if (s < CAP)
            keys[s] = ((unsigned long long)__float_as_uint(vc.y) << 32) | (unsigned long long)(0xFFFFFFFFu - (unsigned)(idx0 + 1)); }
        if (pk2) { int s = base + c0 + c1 + __popcll(b2 & ltmask); if (s < CAP)
            keys[s] = ((unsigned long long)__float_as_uint(vc.z) << 32) | (unsigned long long)(0xFFFFFFFFu - (unsigned)(idx0 + 2)); }
        if (pk3) { int s = base + c0 + c1 + c2 + __popcll(b3 & ltmask); if (s < CAP)
            keys[s] = ((unsigned long long)__float_as_uint(vc.w) << 32) | (unsigned long long)(0xFFFFFFFFu - (unsigned)(idx0 + 3)); }
    }
    __syncthreads();

    const int n = (cnt < CAP) ? cnt : CAP;

    // ---- per-wave top-30 over its 512-key chunk, register-resident ----
    unsigned long long k[8];
    {
        int base0 = wave * 512 + lane;
        #pragma unroll
        for (int i = 0; i < 8; ++i) {
            int p = base0 + i * 64;
            k[i] = (p < n) ? keys[p] : 0ull;
        }
    }
    for (int r = 0; r < PPK; ++r) {
        unsigned long long best = k[0];
        #pragma unroll
        for (int i = 1; i < 8; ++i) best = umax64(best, k[i]);
        #pragma unroll
        for (int off = 1; off < 64; off <<= 1)
            best = umax64(best, (unsigned long long)__shfl_xor((long long)best, off));
        if (best != 0ull) {
            #pragma unroll
            for (int i = 0; i < 8; ++i)
                if (k[i] == best) k[i] = 0ull;     // keys unique when nonzero
        }
        if (lane == 0) sel8[wave * PPK + r] = best;
    }
    __syncthreads();

    // ---- wave 0 merges 240 -> 30 ----
    if (wave == 0) {
        unsigned long long m[4];
        #pragma unroll
        for (int i = 0; i < 4; ++i) {
            int p = lane + i * 64;
            m[i] = (p < 8 * PPK) ? sel8[p] : 0ull;
        }
        for (int r = 0; r < PPK; ++r) {
            unsigned long long best = umax64(umax64(m[0], m[1]), umax64(m[2], m[3]));
            #pragma unroll
            for (int off = 1; off < 64; off <<= 1)
                best = umax64(best, (unsigned long long)__shfl_xor((long long)best, off));
            if (best != 0ull) {
                #pragma unroll
                for (int i = 0; i < 4; ++i)
                    if (m[i] == best) m[i] = 0ull;
            }
            if (lane == 0) sel[r] = best;
        }
    }
    __syncthreads();

    // ---- emit peaks with subpixel refinement (bit-identical to validated) ----
    if (tid < PPK) {
        unsigned long long g = sel[tid];
        float px = 0.0f, py = 0.0f, sc = 0.0f;
        if (g != 0ull) {
            float v = __uint_as_float((unsigned int)(g >> 32));
            int idx = (int)(0xFFFFFFFFu - (unsigned int)(g & 0xFFFFFFFFull));
            int y = idx / WW;
            int x = idx - y * WW;
            float dx = 0.0f, dy = 0.0f;
            if (x > 0 && x < WW - 1 && y > 0 && y < HH - 1) {
                float r_ = hp[y * WW + x + 1];
                float l_ = hp[y * WW + x - 1];
                float dn = hp[(y + 1) * WW + x];
                float up = hp[(y - 1) * WW + x];
                float dx_raw = 0.5f * (r_ - l_);
                float dy_raw = 0.5f * (dn - up);
                float dxx = __fsub_rn(__fadd_rn(r_, l_), 2.0f * v);
                float dyy = __fsub_rn(__fadd_rn(dn, up), 2.0f * v);
                dx = (fabsf(dxx) > 1e-6f) ? (dx_raw / (-dxx)) : dx_raw;
                dy = (fabsf(dyy) > 1e-6f) ? (dy_raw / (-dyy)) : dy_raw;
            }
            px = __fadd_rn((float)x, dx);
            py = __fadd_rn((float)y, dy);
            sc = v;
        }
        float* o = out + ((size_t)ch * PPK + tid) * 3;
        o[0] = px;
        o[1] = py;
        o[2] = sc;
    }
}

// ---------------------------------------------------------------------------
// Kernel 2: PAF connection scoring, double-buffered quarter-plane pipeline.
// One block of 512 threads per (b,l). 8 quarters: pafx q0..q3, pafy q0..q3.
// While gathering quarter q from LDS buf[q&1], quarter q+1 is prefetched
// into registers; after a barrier it is stored to buf[(q+1)&1].
// ---------------------------------------------------------------------------
__global__ __launch_bounds__(512, 6) void conn_kernel(const float* __restrict__ paf,
                                                      const float* __restrict__ peaks,
                                                      float* __restrict__ conn)
{
    const int bl = blockIdx.x;        // b*19 + l
    const int b  = bl / LL;
    const int l  = bl - b * LL;

    __shared__ float buf[2][QCNT];    // 2 x 25.6 KB
    __shared__ float As[PPK * 3];
    __shared__ float Bs[PPK * 3];

    const int tid = threadIdx.x;
    {
        const float* pa = peaks + (((size_t)b * KJ) + d_ska[l]) * (PPK * 3);
        const float* pb = peaks + (((size_t)b * KJ) + d_skb[l]) * (PPK * 3);
        if (tid < PPK * 3)            As[tid] = pa[tid];
        else if (tid < 2 * PPK * 3)   Bs[tid - PPK * 3] = pb[tid - PPK * 3];
    }
    __syncthreads();

    // ---- per-pair precompute (indices + geometry); thread t owns pairs t, t+512 ----
    const int npair = (tid + 512 < PPK * PPK) ? 2 : ((tid < PPK * PPK) ? 1 : 0);
    int   lin[2][SS];
    float accv[2][SS];
    float vxp[2], vyp[2], sap[2], sbp[2];

    for (int q = 0; q < npair; ++q) {
        int p = tid + q * 512;
        int i = p / PPK;
        int j = p - i * PPK;
        float ax = As[i * 3 + 0], ay = As[i * 3 + 1], sa = As[i * 3 + 2];
        float bx = Bs[j * 3 + 0], by = Bs[j * 3 + 1], sb = Bs[j * 3 + 2];
        float dxl = __fsub_rn(bx, ax);
        float dyl = __fsub_rn(by, ay);
        float nsq = __fadd_rn(__fmul_rn(dxl, dxl), __fmul_rn(dyl, dyl));
        float nrm = __fadd_rn(sqrtf(nsq), 1e-8f);
        vxp[q] = dxl / nrm;
        vyp[q] = dyl / nrm;
        sap[q] = sa;
        sbp[q] = sb;
        #pragma unroll
        for (int s = 0; s < SS; ++s) {
            float t  = d_ts[s];
            float xs = __fadd_rn(ax, __fmul_rn(t, dxl));
            float ys = __fadd_rn(ay, __fmul_rn(t, dyl));
            float rx = rintf(xs);               // round half to even, matches jnp.round
            float ry = rintf(ys);
            rx = fminf(fmaxf(rx, 0.0f), (float)(WW - 1));
            ry = fminf(fmaxf(ry, 0.0f), (float)(HH - 1));
            lin[q][s] = (int)ry * WW + (int)rx;  // in [0, HW)
        }
    }

    const float* src = paf + (((size_t)b * (2 * LL)) + 2 * l) * HW;  // pafx; pafy = +HW

    // ---- preload quarter 0 into buf[0] ----
    float4 r0, r1, r2, r3;
    {
        const float4* s4 = (const float4*)src;
        r0 = s4[tid];
        r1 = s4[tid + 512];
        r2 = s4[tid + 1024];
        if (tid < QF4 - 1536) r3 = s4[tid + 1536];
        float4* b4 = (float4*)buf[0];
        b4[tid] = r0;
        b4[tid + 512] = r1;
        b4[tid + 1024] = r2;
        if (tid < QF4 - 1536) b4[tid + 1536] = r3;
    }
    __syncthreads();

    // ---- 8-quarter pipeline ----
    for (int qq = 0; qq < 8; ++qq) {
        const int cur = qq & 1;
        // prefetch next quarter into registers (overlaps with gather below)
        if (qq < 7) {
            const int nq = qq + 1;
            const float4* s4 = (const float4*)(src + (size_t)(nq >> 2) * HW + (nq & 3) * QCNT);
            r0 = s4[tid];
            r1 = s4[tid + 512];
            r2 = s4[tid + 1024];
            if (tid < QF4 - 1536) r3 = s4[tid + 1536];
        }
        // gather current quarter from LDS
        {
            const int comp = qq >> 2;              // 0 = pafx, 1 = pafy
            const int lo   = (qq & 3) * QCNT;
            for (int q = 0; q < npair; ++q) {
                #pragma unroll
                for (int s = 0; s < SS; ++s) {
                    int lrel = lin[q][s] - lo;
                    if ((unsigned)lrel < (unsigned)QCNT) {
                        float v = buf[cur][lrel];
                        if (comp == 0) accv[q][s] = __fmul_rn(v, vxp[q]);
                        else           accv[q][s] = __fadd_rn(accv[q][s], __fmul_rn(v, vyp[q]));
                    }
                }
            }
        }
        __syncthreads();                           // gathers of buf[cur] (and earlier) done
        if (qq < 7) {
            float4* b4 = (float4*)buf[1 - cur];
            b4[tid] = r0;
            b4[tid + 512] = r1;
            b4[tid + 1024] = r2;
            if (tid < QF4 - 1536) b4[tid + 1536] = r3;
            __syncthreads();                       // staging visible before next gather
        }
    }

    // ---- fold + emit ----
    for (int q = 0; q < npair; ++q) {
        int p = tid + q * 512;
        int cntc = 0;
        #pragma unroll
        for (int s = 0; s < SS; ++s)
            if (accv[q][s] > 0.05f) ++cntc;
        float s01 = __fadd_rn(accv[q][0], accv[q][1]);
        float s23 = __fadd_rn(accv[q][2], accv[q][3]);
        float s45 = __fadd_rn(accv[q][4], accv[q][5]);
        float s67 = __fadd_rn(accv[q][6], accv[q][7]);
        float sum = __fadd_rn(__fadd_rn(s01, s23), __fadd_rn(s45, s67));
        sum = __fadd_rn(sum, accv[q][8]);
        sum = __fadd_rn(sum, accv[q][9]);
        float mean = sum / 10.0f;
        bool va = sap[q] > 0.1f;
        bool vb = sbp[q] > 0.1f;
        bool cond = (mean > 0.0f) && (cntc >= 9) && va && vb;  // ratio>0.8 <=> cnt>=9
        float val = 0.0f;
        if (cond) val = __fadd_rn(mean, __fmul_rn(0.5f, __fadd_rn(sap[q], sbp[q])));
        conn[(size_t)bl * (PPK * PPK) + p] = val;
    }
}

extern "C" void kernel_launch(void* const* d_in, const int* in_sizes, int n_in,
                              void* d_out, int out_size, void* d_ws, size_t ws_size,
                              hipStream_t stream)
{
    const float* heat = (const float*)d_in[0];   // [32,17,160,160]
    const float* paf  = (const float*)d_in[1];   // [32,38,160,160]
    float* out = (float*)d_out;

    float* peaks_out = out;                                   // 32*17*30*3 = 48960
    float* conn_out  = out + (size_t)BATCH * KJ * PPK * 3;    // 32*19*30*30 = 547200

    hipLaunchKernelGGL(peaks_kernel, dim3(BATCH * KJ), dim3(512), 0, stream,
                       heat, peaks_out);
    hipLaunchKernelGGL(conn_kernel, dim3(BATCH * LL), dim3(512), 0, stream,
                       paf, peaks_out, conn_out);
}

// Round 5
// 308.844 us; speedup vs baseline: 1.2461x; 1.2461x over previous
//
#include <hip/hip_runtime.h>
#include <cstdint>
#include <cstddef>
#include <cfloat>

// Problem constants (match reference)
static constexpr int BATCH = 32;
static constexpr int KJ    = 17;   // heat channels (joints)
static constexpr int LL    = 19;   // limbs
static constexpr int HH    = 160;
static constexpr int WW    = 160;
static constexpr int PPK   = 30;   // top-k peaks
static constexpr int SS    = 10;   // samples along limb
static constexpr int HW    = HH * WW;
static constexpr int CGW   = WW / 4;        // 40 float4 cells per row
static constexpr int CAP   = 4096;          // candidate capacity per channel (LDS)
static constexpr int NPAIR = PPK * PPK;     // 900
static constexpr int HALFP = NPAIR / 2;     // 450 active threads in conn

// conn quarter-plane staging
static constexpr int QROWS = 40;            // quarter-plane rows
static constexpr int QCNT  = QROWS * WW;    // 6400 floats = 25.6 KB
static constexpr int QF4   = QCNT / 4;      // 1600 float4

__constant__ int d_ska[LL] = {15,13,16,14,11,5,6,5,5,6,7,8,1,0,0,1,2,3,4};
__constant__ int d_skb[LL] = {13,11,14,12,12,11,12,6,7,8,9,10,2,1,2,3,4,5,6};
// t = linspace(0,1,10) in f32 (verified identical to f32(s/9.0))
__constant__ float d_ts[SS] = {
    0.0f,
    (float)(1.0/9.0), (float)(2.0/9.0), (float)(3.0/9.0),
    (float)(4.0/9.0), (float)(5.0/9.0), (float)(6.0/9.0),
    (float)(7.0/9.0), (float)(8.0/9.0),
    1.0f
};

__device__ __forceinline__ float max3f(float a, float b, float c) {
    return fmaxf(fmaxf(a, b), c);
}
__device__ __forceinline__ unsigned long long umax64(unsigned long long a, unsigned long long b) {
    return a > b ? a : b;
}
// async global->LDS DMA: 64 lanes x 16B, lds base wave-uniform, lane i -> base + i*16
__device__ __forceinline__ void async_copy16(const float4* gsrc_lane, float4* lds_wave_base) {
    __builtin_amdgcn_global_load_lds(
        (const __attribute__((address_space(1))) void*)gsrc_lane,
        (__attribute__((address_space(3))) void*)lds_wave_base,
        16, 0, 0);
}

// ---------------------------------------------------------------------------
// Kernel 1: fused per-channel peak detection + top-30 + subpixel refine.
// One block of 1024 threads (16 waves) per (b,k) channel. Branchless separable
// 3x3 max over float4 cells with CLAMPED edge offsets (no divergent edge
// branches); ballot-aggregated append; per-wave register top-30; wave 0
// merges 480->30. Writes (px,py,sc) to out[(ch*30+p)*3+..].
// ---------------------------------------------------------------------------
__global__ __launch_bounds__(1024, 8) void peaks_kernel(const float* __restrict__ heat,
                                                        float* __restrict__ out)
{
    const int ch = blockIdx.x;              // b*17 + k
    const float* hp = heat + (size_t)ch * HW;

    __shared__ unsigned long long keys[CAP];
    __shared__ unsigned long long sel16[16 * PPK];
    __shared__ unsigned long long sel[PPK];
    __shared__ int cnt;

    const int tid  = threadIdx.x;
    const int lane = tid & 63;
    const int wave = tid >> 6;
    const unsigned long long ltmask = ((unsigned long long)1 << lane) - 1ull;

    if (tid == 0) cnt = 0;
    __syncthreads();

    // ---- branchless scan: ~6.25 float4 cells per thread ----
    for (int c = tid; c < HW / 4; c += 1024) {
        int y  = c / CGW;
        int cg = c - y * CGW;
        int x0 = cg * 4;
        int yu = (y > 0) ? y - 1 : 0;
        int yd = (y < HH - 1) ? y + 1 : HH - 1;

        const float* rc = hp + y  * WW + x0;
        const float* ru = hp + yu * WW + x0;
        const float* rd = hp + yd * WW + x0;

        float4 vc = *(const float4*)rc;
        float4 vu = *(const float4*)ru;
        float4 vd = *(const float4*)rd;

        // clamped edge offsets: at edges re-read an interior element that is
        // already in the max window -> identical max, no OOB, no branch.
        int offL = (x0 > 0) ? -1 : 0;
        int offR = (x0 + 4 < WW) ? 4 : 3;
        float lc  = rc[offL], lu  = ru[offL], ld  = rd[offL];
        float rcx = rc[offR], rux = ru[offR], rdx = rd[offR];

        float mu0 = max3f(lu, vu.x, vu.y), mu1 = max3f(vu.x, vu.y, vu.z);
        float mu2 = max3f(vu.y, vu.z, vu.w), mu3 = max3f(vu.z, vu.w, rux);
        float mc0 = max3f(lc, vc.x, vc.y), mc1 = max3f(vc.x, vc.y, vc.z);
        float mc2 = max3f(vc.y, vc.z, vc.w), mc3 = max3f(vc.z, vc.w, rcx);
        float md0 = max3f(ld, vd.x, vd.y), md1 = max3f(vd.x, vd.y, vd.z);
        float md2 = max3f(vd.y, vd.z, vd.w), md3 = max3f(vd.z, vd.w, rdx);

        float nm0 = max3f(mu0, mc0, md0);
        float nm1 = max3f(mu1, mc1, md1);
        float nm2 = max3f(mu2, mc2, md2);
        float nm3 = max3f(mu3, mc3, md3);

        bool pk0 = (vc.x == nm0) && (vc.x > 0.1f);
        bool pk1 = (vc.y == nm1) && (vc.y > 0.1f);
        bool pk2 = (vc.z == nm2) && (vc.z > 0.1f);
        bool pk3 = (vc.w == nm3) && (vc.w > 0.1f);

        unsigned long long b0 = __ballot(pk0);
        unsigned long long b1 = __ballot(pk1);
        unsigned long long b2 = __ballot(pk2);
        unsigned long long b3 = __ballot(pk3);
        int c0 = __popcll(b0), c1 = __popcll(b1), c2 = __popcll(b2), c3 = __popcll(b3);
        int tot = c0 + c1 + c2 + c3;
        int base = 0;
        if (lane == 0 && tot > 0) base = atomicAdd(&cnt, tot);
        base = __shfl(base, 0);

        int idx0 = y * WW + x0;
        if (pk0) { int s = base + __popcll(b0 & ltmask); if (s < CAP)
            keys[s] = ((unsigned long long)__float_as_uint(vc.x) << 32) | (unsigned long long)(0xFFFFFFFFu - (unsigned)(idx0 + 0)); }
        if (pk1) { int s = base + c0 + __popcll(b1 & ltmask); if (s < CAP)
            keys[s] = ((unsigned long long)__float_as_uint(vc.y) << 32) | (unsigned long long)(0xFFFFFFFFu - (unsigned)(idx0 + 1)); }
        if (pk2) { int s = base + c0 + c1 + __popcll(b2 & ltmask); if (s < CAP)
            keys[s] = ((unsigned long long)__float_as_uint(vc.z) << 32) | (unsigned long long)(0xFFFFFFFFu - (unsigned)(idx0 + 2)); }
        if (pk3) { int s = base + c0 + c1 + c2 + __popcll(b3 & ltmask); if (s < CAP)
            keys[s] = ((unsigned long long)__float_as_uint(vc.w) << 32) | (unsigned long long)(0xFFFFFFFFu - (unsigned)(idx0 + 3)); }
    }
    __syncthreads();

    const int n = (cnt < CAP) ? cnt : CAP;

    // ---- per-wave top-30 over its 256-key chunk, register-resident ----
    unsigned long long k[4];
    {
        int base0 = wave * 256 + lane;
        #pragma unroll
        for (int i = 0; i < 4; ++i) {
            int p = base0 + i * 64;
            k[i] = (p < n) ? keys[p] : 0ull;
        }
    }
    for (int r = 0; r < PPK; ++r) {
        unsigned long long best = umax64(umax64(k[0], k[1]), umax64(k[2], k[3]));
        #pragma unroll
        for (int off = 1; off < 64; off <<= 1)
            best = umax64(best, (unsigned long long)__shfl_xor((long long)best, off));
        if (best != 0ull) {
            #pragma unroll
            for (int i = 0; i < 4; ++i)
                if (k[i] == best) k[i] = 0ull;     // keys unique when nonzero
        }
        if (lane == 0) sel16[wave * PPK + r] = best;
    }
    __syncthreads();

    // ---- wave 0 merges 480 -> 30 ----
    if (wave == 0) {
        unsigned long long m[8];
        #pragma unroll
        for (int i = 0; i < 8; ++i) {
            int p = lane + i * 64;
            m[i] = (p < 16 * PPK) ? sel16[p] : 0ull;
        }
        for (int r = 0; r < PPK; ++r) {
            unsigned long long best = 0ull;
            #pragma unroll
            for (int i = 0; i < 8; ++i) best = umax64(best, m[i]);
            #pragma unroll
            for (int off = 1; off < 64; off <<= 1)
                best = umax64(best, (unsigned long long)__shfl_xor((long long)best, off));
            if (best != 0ull) {
                #pragma unroll
                for (int i = 0; i < 8; ++i)
                    if (m[i] == best) m[i] = 0ull;
            }
            if (lane == 0) sel[r] = best;
        }
    }
    __syncthreads();

    // ---- emit peaks with subpixel refinement (bit-identical to validated) ----
    if (tid < PPK) {
        unsigned long long g = sel[tid];
        float px = 0.0f, py = 0.0f, sc = 0.0f;
        if (g != 0ull) {
            float v = __uint_as_float((unsigned int)(g >> 32));
            int idx = (int)(0xFFFFFFFFu - (unsigned int)(g & 0xFFFFFFFFull));
            int y = idx / WW;
            int x = idx - y * WW;
            float dx = 0.0f, dy = 0.0f;
            if (x > 0 && x < WW - 1 && y > 0 && y < HH - 1) {
                float r_ = hp[y * WW + x + 1];
                float l_ = hp[y * WW + x - 1];
                float dn = hp[(y + 1) * WW + x];
                float up = hp[(y - 1) * WW + x];
                float dx_raw = 0.5f * (r_ - l_);
                float dy_raw = 0.5f * (dn - up);
                float dxx = __fsub_rn(__fadd_rn(r_, l_), 2.0f * v);
                float dyy = __fsub_rn(__fadd_rn(dn, up), 2.0f * v);
                dx = (fabsf(dxx) > 1e-6f) ? (dx_raw / (-dxx)) : dx_raw;
                dy = (fabsf(dyy) > 1e-6f) ? (dy_raw / (-dyy)) : dy_raw;
            }
            px = __fadd_rn((float)x, dx);
            py = __fadd_rn((float)y, dy);
            sc = v;
        }
        float* o = out + ((size_t)ch * PPK + tid) * 3;
        o[0] = px;
        o[1] = py;
        o[2] = sc;
    }
}

// ---------------------------------------------------------------------------
// Kernel 2: PAF connection scoring, double-buffered quarter-plane pipeline
// with async global->LDS DMA (no VGPR staging, no spill-prone arrays).
// One block of 512 threads per (b,l). Threads 0..449 own pairs (tid, tid+450);
// threads >=450 are clamped to pair 899 (compute, don't store).
// 8 quarters: pafx q0..q3, pafy q0..q3. One barrier per phase: the compiler's
// vmcnt(0)+lgkmcnt(0) before s_barrier drains both the DMA for the next
// buffer and the gathers of the current one.
// ---------------------------------------------------------------------------
__global__ __launch_bounds__(512, 4) void conn_kernel(const float* __restrict__ paf,
                                                      const float* __restrict__ peaks,
                                                      float* __restrict__ conn)
{
    const int bl = blockIdx.x;        // b*19 + l
    const int b  = bl / LL;
    const int l  = bl - b * LL;

    __shared__ float buf[2][QCNT];    // 2 x 25.6 KB
    __shared__ float As[PPK * 3];
    __shared__ float Bs[PPK * 3];

    const int tid  = threadIdx.x;
    const int lane = tid & 63;
    const int wave = tid >> 6;
    {
        const float* pa = peaks + (((size_t)b * KJ) + d_ska[l]) * (PPK * 3);
        const float* pb = peaks + (((size_t)b * KJ) + d_skb[l]) * (PPK * 3);
        if (tid < PPK * 3)            As[tid] = pa[tid];
        else if (tid < 2 * PPK * 3)   Bs[tid - PPK * 3] = pb[tid - PPK * 3];
    }

    const float*  src  = paf + (((size_t)b * (2 * LL)) + 2 * l) * HW;  // pafx; pafy = +HW
    const float4* src4 = (const float4*)src;

    // ---- kick off DMA of quarter 0 (pafx rows 0-39) into buf[0] ----
    {
        float4* b4 = (float4*)buf[0];
        #pragma unroll
        for (int c = 0; c < 3; ++c)
            async_copy16(src4 + c * 512 + tid, b4 + c * 512 + wave * 64);
        if (wave == 0)
            async_copy16(src4 + 1536 + lane, b4 + 1536);
    }
    __syncthreads();   // drains DMA (vmcnt(0) before barrier) + As/Bs stores

    // ---- per-pair precompute; everything constant-indexed -> registers ----
    const bool active = (tid < HALFP);
    const int p0 = active ? tid : (NPAIR - 1);
    const int p1 = active ? (tid + HALFP) : (NPAIR - 1);

    int   lin[2][SS];
    float accv[2][SS];
    float vxp[2], vyp[2], sap[2], sbp[2];

    #pragma unroll
    for (int q = 0; q < 2; ++q) {
        int p = (q == 0) ? p0 : p1;
        int i = p / PPK;
        int j = p - i * PPK;
        float ax = As[i * 3 + 0], ay = As[i * 3 + 1], sa = As[i * 3 + 2];
        float bx = Bs[j * 3 + 0], by = Bs[j * 3 + 1], sb = Bs[j * 3 + 2];
        float dxl = __fsub_rn(bx, ax);
        float dyl = __fsub_rn(by, ay);
        float nsq = __fadd_rn(__fmul_rn(dxl, dxl), __fmul_rn(dyl, dyl));
        float nrm = __fadd_rn(sqrtf(nsq), 1e-8f);
        vxp[q] = dxl / nrm;
        vyp[q] = dyl / nrm;
        sap[q] = sa;
        sbp[q] = sb;
        #pragma unroll
        for (int s = 0; s < SS; ++s) {
            float t  = d_ts[s];
            float xs = __fadd_rn(ax, __fmul_rn(t, dxl));
            float ys = __fadd_rn(ay, __fmul_rn(t, dyl));
            float rx = rintf(xs);               // round half to even, matches jnp.round
            float ry = rintf(ys);
            rx = fminf(fmaxf(rx, 0.0f), (float)(WW - 1));
            ry = fminf(fmaxf(ry, 0.0f), (float)(HH - 1));
            lin[q][s] = (int)ry * WW + (int)rx;  // in [0, HW)
        }
    }

    // ---- 8-quarter pipeline: DMA next while gathering current ----
    for (int qq = 0; qq < 8; ++qq) {
        const int cur = qq & 1;
        if (qq < 7) {
            const int nq = qq + 1;
            const float4* s4 = (const float4*)(src + (size_t)(nq >> 2) * HW + (nq & 3) * QCNT);
            float4* b4 = (float4*)buf[1 - cur];
            #pragma unroll
            for (int c = 0; c < 3; ++c)
                async_copy16(s4 + c * 512 + tid, b4 + c * 512 + wave * 64);
            if (wave == 0)
                async_copy16(s4 + 1536 + lane, b4 + 1536);
        }
        // gather current quarter from LDS (constant-indexed, fully unrolled)
        const int comp = qq >> 2;              // 0 = pafx, 1 = pafy
        const int lo   = (qq & 3) * QCNT;
        #pragma unroll
        for (int q = 0; q < 2; ++q) {
            #pragma unroll
            for (int s = 0; s < SS; ++s) {
                int lrel = lin[q][s] - lo;
                if ((unsigned)lrel < (unsigned)QCNT) {
                    float v = buf[cur][lrel];
                    if (comp == 0) accv[q][s] = __fmul_rn(v, vxp[q]);
                    else           accv[q][s] = __fadd_rn(accv[q][s], __fmul_rn(v, vyp[q]));
                }
            }
        }
        __syncthreads();   // drains gathers of buf[cur] AND the DMA into buf[1-cur]
    }

    // ---- fold + emit ----
    if (active) {
        #pragma unroll
        for (int q = 0; q < 2; ++q) {
            int p = (q == 0) ? p0 : p1;
            int cntc = 0;
            #pragma unroll
            for (int s = 0; s < SS; ++s)
                if (accv[q][s] > 0.05f) ++cntc;
            float s01 = __fadd_rn(accv[q][0], accv[q][1]);
            float s23 = __fadd_rn(accv[q][2], accv[q][3]);
            float s45 = __fadd_rn(accv[q][4], accv[q][5]);
            float s67 = __fadd_rn(accv[q][6], accv[q][7]);
            float sum = __fadd_rn(__fadd_rn(s01, s23), __fadd_rn(s45, s67));
            sum = __fadd_rn(sum, accv[q][8]);
            sum = __fadd_rn(sum, accv[q][9]);
            float mean = sum / 10.0f;
            bool va = sap[q] > 0.1f;
            bool vb = sbp[q] > 0.1f;
            bool cond = (mean > 0.0f) && (cntc >= 9) && va && vb;  // ratio>0.8 <=> cnt>=9
            float val = 0.0f;
            if (cond) val = __fadd_rn(mean, __fmul_rn(0.5f, __fadd_rn(sap[q], sbp[q])));
            conn[(size_t)bl * NPAIR + p] = val;
        }
    }
}

extern "C" void kernel_launch(void* const* d_in, const int* in_sizes, int n_in,
                              void* d_out, int out_size, void* d_ws, size_t ws_size,
                              hipStream_t stream)
{
    const float* heat = (const float*)d_in[0];   // [32,17,160,160]
    const float* paf  = (const float*)d_in[1];   // [32,38,160,160]
    float* out = (float*)d_out;

    float* peaks_out = out;                                   // 32*17*30*3 = 48960
    float* conn_out  = out + (size_t)BATCH * KJ * PPK * 3;    // 32*19*30*30 = 547200

    hipLaunchKernelGGL(peaks_kernel, dim3(BATCH * KJ), dim3(1024), 0, stream,
                       heat, peaks_out);
    hipLaunchKernelGGL(conn_kernel, dim3(BATCH * LL), dim3(512), 0, stream,
                       paf, peaks_out, conn_out);
}

// Round 6
// 289.402 us; speedup vs baseline: 1.3298x; 1.0672x over previous
//
#include <hip/hip_runtime.h>
#include <cstdint>
#include <cstddef>
#include <cfloat>

// Problem constants (match reference)
static constexpr int BATCH = 32;
static constexpr int KJ    = 17;   // heat channels (joints)
static constexpr int LL    = 19;   // limbs
static constexpr int HH    = 160;
static constexpr int WW    = 160;
static constexpr int PPK   = 30;   // top-k peaks
static constexpr int SS    = 10;   // samples along limb
static constexpr int HW    = HH * WW;
static constexpr int CGW   = WW / 4;        // 40 float4 cells per row
static constexpr int CAP   = 4096;          // candidate capacity per channel (LDS)
static constexpr int HICAP = 512;           // hi-list capacity (v > HITHR)
static constexpr int NPAIR = PPK * PPK;     // 900
static constexpr int HALFP = NPAIR / 2;     // 450 active threads in conn
#define HITHR 0.98f

// conn quarter-plane staging
static constexpr int QROWS = 40;            // quarter-plane rows
static constexpr int QCNT  = QROWS * WW;    // 6400 floats = 25.6 KB
static constexpr int QF4   = QCNT / 4;      // 1600 float4

__constant__ int d_ska[LL] = {15,13,16,14,11,5,6,5,5,6,7,8,1,0,0,1,2,3,4};
__constant__ int d_skb[LL] = {13,11,14,12,12,11,12,6,7,8,9,10,2,1,2,3,4,5,6};
// t = linspace(0,1,10) in f32 (verified identical to f32(s/9.0))
__constant__ float d_ts[SS] = {
    0.0f,
    (float)(1.0/9.0), (float)(2.0/9.0), (float)(3.0/9.0),
    (float)(4.0/9.0), (float)(5.0/9.0), (float)(6.0/9.0),
    (float)(7.0/9.0), (float)(8.0/9.0),
    1.0f
};

__device__ __forceinline__ float max3f(float a, float b, float c) {
    return fmaxf(fmaxf(a, b), c);
}
__device__ __forceinline__ unsigned long long umax64(unsigned long long a, unsigned long long b) {
    return a > b ? a : b;
}
// async global->LDS DMA: 64 lanes x 16B, lds base wave-uniform, lane i -> base + i*16
__device__ __forceinline__ void async_copy16(const float4* gsrc_lane, float4* lds_wave_base) {
    __builtin_amdgcn_global_load_lds(
        (const __attribute__((address_space(1))) void*)gsrc_lane,
        (__attribute__((address_space(3))) void*)lds_wave_base,
        16, 0, 0);
}

// ---------------------------------------------------------------------------
// Kernel 1: fused per-channel peak detection + top-30 + subpixel refine.
// 512 threads (8 waves) per (b,k) channel. Branchless separable 3x3 max with
// clamped edge offsets; ballot-aggregated append to the full candidate list
// AND to a hi-list (v > 0.98). Fast path (hi_n in [30,512]): wave 0 selects
// top-30 from the hi-list alone — provably the global top-30, since with
// >=30 candidates above 0.98 no candidate <=0.98 can rank in the top 30.
// Fallback: full per-wave top-30 + 240->30 merge (validated r4 path).
// ---------------------------------------------------------------------------
__global__ __launch_bounds__(512, 4) void peaks_kernel(const float* __restrict__ heat,
                                                       float* __restrict__ out)
{
    const int ch = blockIdx.x;              // b*17 + k
    const float* hp = heat + (size_t)ch * HW;

    __shared__ unsigned long long keys[CAP];
    __shared__ unsigned long long hikeys[HICAP];
    __shared__ unsigned long long sel8[8 * PPK];
    __shared__ unsigned long long sel[PPK];
    __shared__ int cnt;
    __shared__ int hcnt;

    const int tid  = threadIdx.x;
    const int lane = tid & 63;
    const int wave = tid >> 6;
    const unsigned long long ltmask = ((unsigned long long)1 << lane) - 1ull;

    if (tid == 0) { cnt = 0; hcnt = 0; }
    __syncthreads();

    // ---- branchless scan: 12.5 float4 cells per thread ----
    for (int c = tid; c < HW / 4; c += 512) {
        int y  = c / CGW;
        int cg = c - y * CGW;
        int x0 = cg * 4;
        int yu = (y > 0) ? y - 1 : 0;
        int yd = (y < HH - 1) ? y + 1 : HH - 1;

        const float* rc = hp + y  * WW + x0;
        const float* ru = hp + yu * WW + x0;
        const float* rd = hp + yd * WW + x0;

        float4 vc = *(const float4*)rc;
        float4 vu = *(const float4*)ru;
        float4 vd = *(const float4*)rd;

        // clamped edge offsets: at edges re-read an interior element already
        // inside the max window -> identical max, no OOB, no branch.
        int offL = (x0 > 0) ? -1 : 0;
        int offR = (x0 + 4 < WW) ? 4 : 3;
        float lc  = rc[offL], lu  = ru[offL], ld  = rd[offL];
        float rcx = rc[offR], rux = ru[offR], rdx = rd[offR];

        float mu0 = max3f(lu, vu.x, vu.y), mu1 = max3f(vu.x, vu.y, vu.z);
        float mu2 = max3f(vu.y, vu.z, vu.w), mu3 = max3f(vu.z, vu.w, rux);
        float mc0 = max3f(lc, vc.x, vc.y), mc1 = max3f(vc.x, vc.y, vc.z);
        float mc2 = max3f(vc.y, vc.z, vc.w), mc3 = max3f(vc.z, vc.w, rcx);
        float md0 = max3f(ld, vd.x, vd.y), md1 = max3f(vd.x, vd.y, vd.z);
        float md2 = max3f(vd.y, vd.z, vd.w), md3 = max3f(vd.z, vd.w, rdx);

        float nm0 = max3f(mu0, mc0, md0);
        float nm1 = max3f(mu1, mc1, md1);
        float nm2 = max3f(mu2, mc2, md2);
        float nm3 = max3f(mu3, mc3, md3);

        bool pk0 = (vc.x == nm0) && (vc.x > 0.1f);
        bool pk1 = (vc.y == nm1) && (vc.y > 0.1f);
        bool pk2 = (vc.z == nm2) && (vc.z > 0.1f);
        bool pk3 = (vc.w == nm3) && (vc.w > 0.1f);

        int idx0 = y * WW + x0;
        unsigned long long key0 = ((unsigned long long)__float_as_uint(vc.x) << 32) | (unsigned long long)(0xFFFFFFFFu - (unsigned)(idx0 + 0));
        unsigned long long key1 = ((unsigned long long)__float_as_uint(vc.y) << 32) | (unsigned long long)(0xFFFFFFFFu - (unsigned)(idx0 + 1));
        unsigned long long key2 = ((unsigned long long)__float_as_uint(vc.z) << 32) | (unsigned long long)(0xFFFFFFFFu - (unsigned)(idx0 + 2));
        unsigned long long key3 = ((unsigned long long)__float_as_uint(vc.w) << 32) | (unsigned long long)(0xFFFFFFFFu - (unsigned)(idx0 + 3));

        // full-list append
        {
            unsigned long long b0 = __ballot(pk0);
            unsigned long long b1 = __ballot(pk1);
            unsigned long long b2 = __ballot(pk2);
            unsigned long long b3 = __ballot(pk3);
            int c0 = __popcll(b0), c1 = __popcll(b1), c2 = __popcll(b2), c3 = __popcll(b3);
            int tot = c0 + c1 + c2 + c3;
            int base = 0;
            if (lane == 0 && tot > 0) base = atomicAdd(&cnt, tot);
            base = __shfl(base, 0);
            if (pk0) { int s = base + __popcll(b0 & ltmask); if (s < CAP) keys[s] = key0; }
            if (pk1) { int s = base + c0 + __popcll(b1 & ltmask); if (s < CAP) keys[s] = key1; }
            if (pk2) { int s = base + c0 + c1 + __popcll(b2 & ltmask); if (s < CAP) keys[s] = key2; }
            if (pk3) { int s = base + c0 + c1 + c2 + __popcll(b3 & ltmask); if (s < CAP) keys[s] = key3; }
        }
        // hi-list append (v > HITHR)
        {
            bool h0 = pk0 && (vc.x > HITHR);
            bool h1 = pk1 && (vc.y > HITHR);
            bool h2 = pk2 && (vc.z > HITHR);
            bool h3 = pk3 && (vc.w > HITHR);
            unsigned long long b0 = __ballot(h0);
            unsigned long long b1 = __ballot(h1);
            unsigned long long b2 = __ballot(h2);
            unsigned long long b3 = __ballot(h3);
            int c0 = __popcll(b0), c1 = __popcll(b1), c2 = __popcll(b2), c3 = __popcll(b3);
            int tot = c0 + c1 + c2 + c3;
            int base = 0;
            if (lane == 0 && tot > 0) base = atomicAdd(&hcnt, tot);
            base = __shfl(base, 0);
            if (h0) { int s = base + __popcll(b0 & ltmask); if (s < HICAP) hikeys[s] = key0; }
            if (h1) { int s = base + c0 + __popcll(b1 & ltmask); if (s < HICAP) hikeys[s] = key1; }
            if (h2) { int s = base + c0 + c1 + __popcll(b2 & ltmask); if (s < HICAP) hikeys[s] = key2; }
            if (h3) { int s = base + c0 + c1 + c2 + __popcll(b3 & ltmask); if (s < HICAP) hikeys[s] = key3; }
        }
    }
    __syncthreads();

    const int hn = hcnt;
    if (hn >= PPK && hn <= HICAP) {
        // ---- FAST PATH: wave 0 alone selects top-30 from hi-list ----
        if (wave == 0) {
            unsigned long long k[8];
            #pragma unroll
            for (int i = 0; i < 8; ++i) {
                int p = lane + i * 64;
                k[i] = (p < hn) ? hikeys[p] : 0ull;
            }
            for (int r = 0; r < PPK; ++r) {
                unsigned long long best = 0ull;
                #pragma unroll
                for (int i = 0; i < 8; ++i) best = umax64(best, k[i]);
                #pragma unroll
                for (int off = 1; off < 64; off <<= 1)
                    best = umax64(best, (unsigned long long)__shfl_xor((long long)best, off));
                if (best != 0ull) {
                    #pragma unroll
                    for (int i = 0; i < 8; ++i)
                        if (k[i] == best) k[i] = 0ull;     // keys unique when nonzero
                }
                if (lane == 0) sel[r] = best;
            }
        }
    } else {
        // ---- FALLBACK: full per-wave top-30 + merge (validated r4 path) ----
        const int n = (cnt < CAP) ? cnt : CAP;
        unsigned long long k[8];
        {
            int base0 = wave * 512 + lane;
            #pragma unroll
            for (int i = 0; i < 8; ++i) {
                int p = base0 + i * 64;
                k[i] = (p < n) ? keys[p] : 0ull;
            }
        }
        for (int r = 0; r < PPK; ++r) {
            unsigned long long best = 0ull;
            #pragma unroll
            for (int i = 0; i < 8; ++i) best = umax64(best, k[i]);
            #pragma unroll
            for (int off = 1; off < 64; off <<= 1)
                best = umax64(best, (unsigned long long)__shfl_xor((long long)best, off));
            if (best != 0ull) {
                #pragma unroll
                for (int i = 0; i < 8; ++i)
                    if (k[i] == best) k[i] = 0ull;
            }
            if (lane == 0) sel8[wave * PPK + r] = best;
        }
        __syncthreads();
        if (wave == 0) {
            unsigned long long m[4];
            #pragma unroll
            for (int i = 0; i < 4; ++i) {
                int p = lane + i * 64;
                m[i] = (p < 8 * PPK) ? sel8[p] : 0ull;
            }
            for (int r = 0; r < PPK; ++r) {
                unsigned long long best = umax64(umax64(m[0], m[1]), umax64(m[2], m[3]));
                #pragma unroll
                for (int off = 1; off < 64; off <<= 1)
                    best = umax64(best, (unsigned long long)__shfl_xor((long long)best, off));
                if (best != 0ull) {
                    #pragma unroll
                    for (int i = 0; i < 4; ++i)
                        if (m[i] == best) m[i] = 0ull;
                }
                if (lane == 0) sel[r] = best;
            }
        }
    }
    __syncthreads();

    // ---- emit peaks with subpixel refinement (bit-identical to validated) ----
    if (tid < PPK) {
        unsigned long long g = sel[tid];
        float px = 0.0f, py = 0.0f, sc = 0.0f;
        if (g != 0ull) {
            float v = __uint_as_float((unsigned int)(g >> 32));
            int idx = (int)(0xFFFFFFFFu - (unsigned int)(g & 0xFFFFFFFFull));
            int y = idx / WW;
            int x = idx - y * WW;
            float dx = 0.0f, dy = 0.0f;
            if (x > 0 && x < WW - 1 && y > 0 && y < HH - 1) {
                float r_ = hp[y * WW + x + 1];
                float l_ = hp[y * WW + x - 1];
                float dn = hp[(y + 1) * WW + x];
                float up = hp[(y - 1) * WW + x];
                float dx_raw = 0.5f * (r_ - l_);
                float dy_raw = 0.5f * (dn - up);
                float dxx = __fsub_rn(__fadd_rn(r_, l_), 2.0f * v);
                float dyy = __fsub_rn(__fadd_rn(dn, up), 2.0f * v);
                dx = (fabsf(dxx) > 1e-6f) ? (dx_raw / (-dxx)) : dx_raw;
                dy = (fabsf(dyy) > 1e-6f) ? (dy_raw / (-dyy)) : dy_raw;
            }
            px = __fadd_rn((float)x, dx);
            py = __fadd_rn((float)y, dy);
            sc = v;
        }
        float* o = out + ((size_t)ch * PPK + tid) * 3;
        o[0] = px;
        o[1] = py;
        o[2] = sc;
    }
}

// ---------------------------------------------------------------------------
// Kernel 2: PAF connection scoring — UNCHANGED from validated round 5.
// Double-buffered quarter-plane pipeline with async global->LDS DMA.
// ---------------------------------------------------------------------------
__global__ __launch_bounds__(512, 4) void conn_kernel(const float* __restrict__ paf,
                                                      const float* __restrict__ peaks,
                                                      float* __restrict__ conn)
{
    const int bl = blockIdx.x;        // b*19 + l
    const int b  = bl / LL;
    const int l  = bl - b * LL;

    __shared__ float buf[2][QCNT];    // 2 x 25.6 KB
    __shared__ float As[PPK * 3];
    __shared__ float Bs[PPK * 3];

    const int tid  = threadIdx.x;
    const int lane = tid & 63;
    const int wave = tid >> 6;
    {
        const float* pa = peaks + (((size_t)b * KJ) + d_ska[l]) * (PPK * 3);
        const float* pb = peaks + (((size_t)b * KJ) + d_skb[l]) * (PPK * 3);
        if (tid < PPK * 3)            As[tid] = pa[tid];
        else if (tid < 2 * PPK * 3)   Bs[tid - PPK * 3] = pb[tid - PPK * 3];
    }

    const float*  src  = paf + (((size_t)b * (2 * LL)) + 2 * l) * HW;  // pafx; pafy = +HW
    const float4* src4 = (const float4*)src;

    // ---- kick off DMA of quarter 0 (pafx rows 0-39) into buf[0] ----
    {
        float4* b4 = (float4*)buf[0];
        #pragma unroll
        for (int c = 0; c < 3; ++c)
            async_copy16(src4 + c * 512 + tid, b4 + c * 512 + wave * 64);
        if (wave == 0)
            async_copy16(src4 + 1536 + lane, b4 + 1536);
    }
    __syncthreads();   // drains DMA (vmcnt(0) before barrier) + As/Bs stores

    // ---- per-pair precompute; everything constant-indexed -> registers ----
    const bool active = (tid < HALFP);
    const int p0 = active ? tid : (NPAIR - 1);
    const int p1 = active ? (tid + HALFP) : (NPAIR - 1);

    int   lin[2][SS];
    float accv[2][SS];
    float vxp[2], vyp[2], sap[2], sbp[2];

    #pragma unroll
    for (int q = 0; q < 2; ++q) {
        int p = (q == 0) ? p0 : p1;
        int i = p / PPK;
        int j = p - i * PPK;
        float ax = As[i * 3 + 0], ay = As[i * 3 + 1], sa = As[i * 3 + 2];
        float bx = Bs[j * 3 + 0], by = Bs[j * 3 + 1], sb = Bs[j * 3 + 2];
        float dxl = __fsub_rn(bx, ax);
        float dyl = __fsub_rn(by, ay);
        float nsq = __fadd_rn(__fmul_rn(dxl, dxl), __fmul_rn(dyl, dyl));
        float nrm = __fadd_rn(sqrtf(nsq), 1e-8f);
        vxp[q] = dxl / nrm;
        vyp[q] = dyl / nrm;
        sap[q] = sa;
        sbp[q] = sb;
        #pragma unroll
        for (int s = 0; s < SS; ++s) {
            float t  = d_ts[s];
            float xs = __fadd_rn(ax, __fmul_rn(t, dxl));
            float ys = __fadd_rn(ay, __fmul_rn(t, dyl));
            float rx = rintf(xs);               // round half to even, matches jnp.round
            float ry = rintf(ys);
            rx = fminf(fmaxf(rx, 0.0f), (float)(WW - 1));
            ry = fminf(fmaxf(ry, 0.0f), (float)(HH - 1));
            lin[q][s] = (int)ry * WW + (int)rx;  // in [0, HW)
        }
    }

    // ---- 8-quarter pipeline: DMA next while gathering current ----
    for (int qq = 0; qq < 8; ++qq) {
        const int cur = qq & 1;
        if (qq < 7) {
            const int nq = qq + 1;
            const float4* s4 = (const float4*)(src + (size_t)(nq >> 2) * HW + (nq & 3) * QCNT);
            float4* b4 = (float4*)buf[1 - cur];
            #pragma unroll
            for (int c = 0; c < 3; ++c)
                async_copy16(s4 + c * 512 + tid, b4 + c * 512 + wave * 64);
            if (wave == 0)
                async_copy16(s4 + 1536 + lane, b4 + 1536);
        }
        // gather current quarter from LDS (constant-indexed, fully unrolled)
        const int comp = qq >> 2;              // 0 = pafx, 1 = pafy
        const int lo   = (qq & 3) * QCNT;
        #pragma unroll
        for (int q = 0; q < 2; ++q) {
            #pragma unroll
            for (int s = 0; s < SS; ++s) {
                int lrel = lin[q][s] - lo;
                if ((unsigned)lrel < (unsigned)QCNT) {
                    float v = buf[cur][lrel];
                    if (comp == 0) accv[q][s] = __fmul_rn(v, vxp[q]);
                    else           accv[q][s] = __fadd_rn(accv[q][s], __fmul_rn(v, vyp[q]));
                }
            }
        }
        __syncthreads();   // drains gathers of buf[cur] AND the DMA into buf[1-cur]
    }

    // ---- fold + emit ----
    if (active) {
        #pragma unroll
        for (int q = 0; q < 2; ++q) {
            int p = (q == 0) ? p0 : p1;
            int cntc = 0;
            #pragma unroll
            for (int s = 0; s < SS; ++s)
                if (accv[q][s] > 0.05f) ++cntc;
            float s01 = __fadd_rn(accv[q][0], accv[q][1]);
            float s23 = __fadd_rn(accv[q][2], accv[q][3]);
            float s45 = __fadd_rn(accv[q][4], accv[q][5]);
            float s67 = __fadd_rn(accv[q][6], accv[q][7]);
            float sum = __fadd_rn(__fadd_rn(s01, s23), __fadd_rn(s45, s67));
            sum = __fadd_rn(sum, accv[q][8]);
            sum = __fadd_rn(sum, accv[q][9]);
            float mean = sum / 10.0f;
            bool va = sap[q] > 0.1f;
            bool vb = sbp[q] > 0.1f;
            bool cond = (mean > 0.0f) && (cntc >= 9) && va && vb;  // ratio>0.8 <=> cnt>=9
            float val = 0.0f;
            if (cond) val = __fadd_rn(mean, __fmul_rn(0.5f, __fadd_rn(sap[q], sbp[q])));
            conn[(size_t)bl * NPAIR + p] = val;
        }
    }
}

extern "C" void kernel_launch(void* const* d_in, const int* in_sizes, int n_in,
                              void* d_out, int out_size, void* d_ws, size_t ws_size,
                              hipStream_t stream)
{
    const float* heat = (const float*)d_in[0];   // [32,17,160,160]
    const float* paf  = (const float*)d_in[1];   // [32,38,160,160]
    float* out = (float*)d_out;

    float* peaks_out = out;                                   // 32*17*30*3 = 48960
    float* conn_out  = out + (size_t)BATCH * KJ * PPK * 3;    // 32*19*30*30 = 547200

    hipLaunchKernelGGL(peaks_kernel, dim3(BATCH * KJ), dim3(512), 0, stream,
                       heat, peaks_out);
    hipLaunchKernelGGL(conn_kernel, dim3(BATCH * LL), dim3(512), 0, stream,
                       paf, peaks_out, conn_out);
}